// Round 5
// baseline (5811.619 us; speedup 1.0000x reference)
//
#include <hip/hip_runtime.h>
#include <hip/hip_fp16.h>

#define N_USERS 200000
#define N_ITEMS 100000
#define N_NODES 300000   // N_USERS + N_ITEMS
#define DIM 64
#define N_EDGES 5000000

#define BROWS 128                             // rows per bucket
#define NB ((N_NODES + BROWS - 1) / BROWS)    // 2344 buckets
#define NPART 8                               // block-parity partitions (XCD-aligned)
#define NC (NB * NPART)                       // 18752 (bucket,part) counters
#define SCAN_BLOCKS ((NC + 255) / 256)        // 74
#define RSHIFT 20
#define CMASK ((1u << RSHIFT) - 1)            // col fits 19 bits (300000 < 2^19)

// ---------------------------------------------------------------------------
// step 1: histogram of (bucket, partition). partition = blockIdx & 7 so the
// same edge->counter mapping is reproduced by bin_fill.
// ---------------------------------------------------------------------------
__global__ void hist_bins(const int* __restrict__ rows, int* __restrict__ bcnt) {
    int e = blockIdx.x * 256 + threadIdx.x;
    if (e >= N_EDGES) return;
    int p = blockIdx.x & (NPART - 1);
    int b = rows[e] >> 7;
    atomicAdd(&bcnt[b * NPART + p], 1);
}

// ---------------------------------------------------------------------------
// generic 3-phase exclusive scan over n counters
// ---------------------------------------------------------------------------
__global__ void scan_block_g(const int* __restrict__ in, int* __restrict__ out,
                             int* __restrict__ bsums, int n) {
    __shared__ int s[256];
    int i = blockIdx.x * 256 + threadIdx.x;
    int v = (i < n) ? in[i] : 0;
    s[threadIdx.x] = v;
    __syncthreads();
    for (int off = 1; off < 256; off <<= 1) {
        int t = (threadIdx.x >= off) ? s[threadIdx.x - off] : 0;
        __syncthreads();
        s[threadIdx.x] += t;
        __syncthreads();
    }
    if (i < n) out[i] = s[threadIdx.x] - v;     // exclusive within block
    if (threadIdx.x == 255) bsums[blockIdx.x] = s[255];
}

__global__ void scan_sums_g(int* __restrict__ bsums, int nb) {
    __shared__ int s[256];
    __shared__ int carry;
    if (threadIdx.x == 0) carry = 0;
    __syncthreads();
    for (int base = 0; base < nb; base += 256) {
        int i = base + threadIdx.x;
        int v = (i < nb) ? bsums[i] : 0;
        s[threadIdx.x] = v;
        __syncthreads();
        for (int off = 1; off < 256; off <<= 1) {
            int t = (threadIdx.x >= off) ? s[threadIdx.x - off] : 0;
            __syncthreads();
            s[threadIdx.x] += t;
            __syncthreads();
        }
        if (i < nb) bsums[i] = carry + s[threadIdx.x] - v;
        __syncthreads();
        if (threadIdx.x == 255) carry += s[255];
        __syncthreads();
    }
}

// add block offsets; copy to cursor; set sentinel
__global__ void finalize_g(int* __restrict__ boff, const int* __restrict__ bsums,
                           int* __restrict__ bcur) {
    int i = blockIdx.x * 256 + threadIdx.x;
    if (i < NC) {
        int v = boff[i] + bsums[blockIdx.x];
        boff[i] = v;
        bcur[i] = v;
    }
    if (i == 0) boff[NC] = N_EDGES;
}

// ---------------------------------------------------------------------------
// step 2: bin edges into (bucket, partition) regions (unsorted within bucket).
// Entry: x = (localrow << 20) | col, y = weight bits.
// ---------------------------------------------------------------------------
__global__ void bin_fill(const int* __restrict__ rows, const int* __restrict__ cols,
                         const float* __restrict__ w,
                         int* __restrict__ bcur, uint2* __restrict__ ent) {
    int e = blockIdx.x * 256 + threadIdx.x;
    if (e >= N_EDGES) return;
    int p = blockIdx.x & (NPART - 1);
    int r = rows[e];
    int pos = atomicAdd(&bcur[(r >> 7) * NPART + p], 1);
    ent[pos] = make_uint2(((unsigned)(r & 127) << RSHIFT) | (unsigned)cols[e],
                          __float_as_uint(w[e]));
}

// ---------------------------------------------------------------------------
// init: A16 = fp16(concat(user,item))
// ---------------------------------------------------------------------------
__global__ void init_f16(const float4* __restrict__ user,
                         const float4* __restrict__ item,
                         uint2* __restrict__ A16) {
    int i = blockIdx.x * blockDim.x + threadIdx.x;
    const int n = N_NODES * (DIM / 4);
    if (i >= n) return;
    const int userN = N_USERS * (DIM / 4);
    float4 v = (i < userN) ? user[i] : item[i - userN];
    __half2 h01 = __floats2half2_rn(v.x, v.y);
    __half2 h23 = __floats2half2_rn(v.z, v.w);
    uint2 st;
    st.x = *reinterpret_cast<unsigned*>(&h01);
    st.y = *reinterpret_cast<unsigned*>(&h23);
    A16[i] = st;
}

// ---------------------------------------------------------------------------
// bucket pull: one workgroup per 128-row bucket, unsorted entries.
// LDS f32 accumulator [128][64] (32KB). Each wave consumes 8 entries/iter:
// 8 entry loads, then 8 independent gathers (full MLP), then 8 ds_add_f32
// (lane->bank 2-way aliased = conflict-free). Tail via weight-zero clamping.
// Epilogue: FINAL=0 -> dst f16;  FINAL=1 -> out = (l0 + L1 + L2 + acc)/4.
// ---------------------------------------------------------------------------
template <int FINAL>
__global__ void pull_bucket(const __half* __restrict__ src,
                            __half* __restrict__ dst,
                            const int* __restrict__ boff,
                            const uint2* __restrict__ ent,
                            const float* __restrict__ user,
                            const float* __restrict__ item,
                            const __half* __restrict__ L1,
                            const __half* __restrict__ L2,
                            float* __restrict__ out) {
    __shared__ float acc[BROWS * DIM];   // 32 KB
    int b = blockIdx.x;
    int tid = threadIdx.x;
    int lane = tid & 63;
    int wv = tid >> 6;                   // wave 0..3

    int beg = boff[b * NPART];
    int end = boff[b * NPART + NPART];

    for (int i = tid; i < BROWS * DIM; i += 256) acc[i] = 0.0f;
    __syncthreads();

    for (int p0 = beg + wv * 8; p0 < end; p0 += 32) {
        uint2 es[8];
        #pragma unroll
        for (int j = 0; j < 8; ++j) {
            int p = p0 + j;
            int pc = (p < end) ? p : (end - 1);
            uint2 e = ent[pc];
            if (p >= end) e.y = 0u;      // weight := 0 for clamped tail
            es[j] = e;
        }
        float v[8];
        #pragma unroll
        for (int j = 0; j < 8; ++j) {
            unsigned col = es[j].x & CMASK;
            v[j] = __half2float(src[(size_t)col * DIM + lane]);
        }
        #pragma unroll
        for (int j = 0; j < 8; ++j) {
            unsigned lr = es[j].x >> RSHIFT;
            atomicAdd(&acc[lr * DIM + lane], __uint_as_float(es[j].y) * v[j]);
        }
    }
    __syncthreads();

    int row0 = b * BROWS;
    if (FINAL) {
        for (int i = tid; i < BROWS * DIM; i += 256) {
            int r = row0 + (i >> 6);
            if (r >= N_NODES) break;
            int d = i & 63;
            size_t gi = (size_t)r * DIM + d;
            float l0 = (r < N_USERS) ? user[gi]
                                     : item[(size_t)(r - N_USERS) * DIM + d];
            float s = l0 + __half2float(L1[gi]) + __half2float(L2[gi]) + acc[i];
            out[gi] = s * 0.25f;
        }
    } else {
        for (int i = tid; i < BROWS * DIM; i += 256) {
            int r = row0 + (i >> 6);
            if (r >= N_NODES) break;
            dst[(size_t)r * DIM + (i & 63)] = __float2half_rn(acc[i]);
        }
    }
}

extern "C" void kernel_launch(void* const* d_in, const int* in_sizes, int n_in,
                              void* d_out, int out_size, void* d_ws, size_t ws_size,
                              hipStream_t stream) {
    const float* user_w = (const float*)d_in[0];
    const float* item_w = (const float*)d_in[1];
    const int*   eidx   = (const int*)d_in[2];
    const float* ew     = (const float*)d_in[3];

    const int* rows = eidx;             // edge_index[0] (destination)
    const int* cols = eidx + N_EDGES;   // edge_index[1] (source)

    float* out = (float*)d_out;

    // workspace layout (~156 MB)
    __half* A16  = (__half*)d_ws;                            // 38.4 MB (layer0 f16)
    __half* B16  = A16 + (size_t)N_NODES * DIM;              // 38.4 MB (L1)
    __half* C16  = B16 + (size_t)N_NODES * DIM;              // 38.4 MB (L2)
    uint2*  ent  = (uint2*)(C16 + (size_t)N_NODES * DIM);    // 40 MB (binned)
    int*    boff = (int*)(ent + N_EDGES);                    // NC+1
    int*    bcur = boff + (NC + 1);                          // NC
    int*    bcnt = bcur + NC;                                // NC
    int*    bsums = bcnt + NC;                               // SCAN_BLOCKS

    const int edge_blocks = (N_EDGES + 255) / 256;
    const int node_vec_blocks = (N_NODES * (DIM / 4) + 255) / 256;

    // ---- bin edges by 128-row bucket (unsorted within bucket) ----
    hipMemsetAsync(bcnt, 0, (size_t)NC * sizeof(int), stream);
    hist_bins<<<edge_blocks, 256, 0, stream>>>(rows, bcnt);
    scan_block_g<<<SCAN_BLOCKS, 256, 0, stream>>>(bcnt, boff, bsums, NC);
    scan_sums_g<<<1, 256, 0, stream>>>(bsums, SCAN_BLOCKS);
    finalize_g<<<SCAN_BLOCKS, 256, 0, stream>>>(boff, bsums, bcur);
    bin_fill<<<edge_blocks, 256, 0, stream>>>(rows, cols, ew, bcur, ent);

    // ---- layer-0 fp16 snapshot ----
    init_f16<<<node_vec_blocks, 256, 0, stream>>>(
        (const float4*)user_w, (const float4*)item_w, (uint2*)A16);

    // ---- 3 pull layers; #3 fuses the final combine ----
    pull_bucket<0><<<NB, 256, 0, stream>>>(A16, B16, boff, ent,
                                           nullptr, nullptr, nullptr, nullptr, nullptr);
    pull_bucket<0><<<NB, 256, 0, stream>>>(B16, C16, boff, ent,
                                           nullptr, nullptr, nullptr, nullptr, nullptr);
    pull_bucket<1><<<NB, 256, 0, stream>>>(C16, nullptr, boff, ent,
                                           user_w, item_w, B16, C16, out);
}

// Round 6
// 974.409 us; speedup vs baseline: 5.9643x; 5.9643x over previous
//
#include <hip/hip_runtime.h>
#include <hip/hip_fp16.h>

#define N_USERS 200000
#define N_ITEMS 100000
#define N_NODES 300000   // N_USERS + N_ITEMS
#define DIM 64
#define N_EDGES 5000000

#define BROWS 64                              // rows per bucket
#define NB ((N_NODES + BROWS - 1) / BROWS)    // 4688 buckets
#define NPART 8                               // block-parity partitions per bucket
#define NC (NB * NPART)                       // 37504 (bucket,part) counters
#define SCAN_BLOCKS ((NC + 255) / 256)        // 147
#define COL_MASK ((1u << 26) - 1)

// ---------------------------------------------------------------------------
// step 1: histogram of (bucket, partition). partition = blockIdx & 7 so the
// same edge->counter mapping is reproduced by bin_fill.
// ---------------------------------------------------------------------------
__global__ void hist_bins(const int* __restrict__ rows, int* __restrict__ bcnt) {
    int e = blockIdx.x * 256 + threadIdx.x;
    if (e >= N_EDGES) return;
    int p = blockIdx.x & (NPART - 1);
    int b = rows[e] >> 6;
    atomicAdd(&bcnt[b * NPART + p], 1);
}

// ---------------------------------------------------------------------------
// generic 3-phase exclusive scan
// ---------------------------------------------------------------------------
__global__ void scan_block_g(const int* __restrict__ in, int* __restrict__ out,
                             int* __restrict__ bsums, int n) {
    __shared__ int s[256];
    int i = blockIdx.x * 256 + threadIdx.x;
    int v = (i < n) ? in[i] : 0;
    s[threadIdx.x] = v;
    __syncthreads();
    for (int off = 1; off < 256; off <<= 1) {
        int t = (threadIdx.x >= off) ? s[threadIdx.x - off] : 0;
        __syncthreads();
        s[threadIdx.x] += t;
        __syncthreads();
    }
    if (i < n) out[i] = s[threadIdx.x] - v;     // exclusive within block
    if (threadIdx.x == 255) bsums[blockIdx.x] = s[255];
}

__global__ void scan_sums_g(int* __restrict__ bsums, int nb) {
    __shared__ int s[256];
    __shared__ int carry;
    if (threadIdx.x == 0) carry = 0;
    __syncthreads();
    for (int base = 0; base < nb; base += 256) {
        int i = base + threadIdx.x;
        int v = (i < nb) ? bsums[i] : 0;
        s[threadIdx.x] = v;
        __syncthreads();
        for (int off = 1; off < 256; off <<= 1) {
            int t = (threadIdx.x >= off) ? s[threadIdx.x - off] : 0;
            __syncthreads();
            s[threadIdx.x] += t;
            __syncthreads();
        }
        if (i < nb) bsums[i] = carry + s[threadIdx.x] - v;
        __syncthreads();
        if (threadIdx.x == 255) carry += s[255];
        __syncthreads();
    }
}

// add block offsets; copy to cursor; set sentinels
__global__ void finalize_g(int* __restrict__ boff, const int* __restrict__ bsums,
                           int* __restrict__ bcur, int* __restrict__ row_ptr) {
    int i = blockIdx.x * 256 + threadIdx.x;
    if (i < NC) {
        int v = boff[i] + bsums[blockIdx.x];
        boff[i] = v;
        bcur[i] = v;
    }
    if (i == 0) {
        boff[NC] = N_EDGES;
        row_ptr[N_NODES] = N_EDGES;
    }
}

// ---------------------------------------------------------------------------
// step 2: bin edges into (bucket, partition) regions.
// Entry: x = (localrow << 26) | col, y = weight bits.
// ---------------------------------------------------------------------------
__global__ void bin_fill(const int* __restrict__ rows, const int* __restrict__ cols,
                         const float* __restrict__ w,
                         int* __restrict__ bcur, uint2* __restrict__ ent1) {
    int e = blockIdx.x * 256 + threadIdx.x;
    if (e >= N_EDGES) return;
    int p = blockIdx.x & (NPART - 1);
    int r = rows[e];
    int pos = atomicAdd(&bcur[(r >> 6) * NPART + p], 1);
    ent1[pos] = make_uint2(((unsigned)(r & 63) << 26) | (unsigned)cols[e],
                           __float_as_uint(w[e]));
}

// ---------------------------------------------------------------------------
// step 3: one workgroup per bucket — sort its region by local row, emit
// row_ptr. All traffic ~8.5KB per bucket, L2-resident.
// ---------------------------------------------------------------------------
__global__ void sort_buckets(const uint2* __restrict__ ent1, uint2* __restrict__ ent2,
                             const int* __restrict__ boff, int* __restrict__ row_ptr) {
    __shared__ int cnt[BROWS];
    __shared__ int cur[BROWS];
    int b = blockIdx.x;
    int tid = threadIdx.x;
    int beg = boff[b * NPART];
    int end = boff[b * NPART + NPART];   // contiguous: bucket-major counter order

    if (tid < BROWS) cnt[tid] = 0;
    __syncthreads();
    for (int i = beg + tid; i < end; i += 256)
        atomicAdd(&cnt[ent1[i].x >> 26], 1);
    __syncthreads();
    if (tid == 0) {                      // exclusive scan of 64 counts
        int acc = 0;
        for (int r = 0; r < BROWS; ++r) { int c = cnt[r]; cnt[r] = acc; acc += c; }
    }
    __syncthreads();
    int row0 = b * BROWS;
    if (tid < BROWS && row0 + tid < N_NODES) {
        int base = beg + cnt[tid];
        row_ptr[row0 + tid] = base;
        cur[tid] = base;
    }
    __syncthreads();
    for (int i = beg + tid; i < end; i += 256) {
        uint2 e = ent1[i];
        int pos = atomicAdd(&cur[e.x >> 26], 1);
        ent2[pos] = make_uint2(e.x & COL_MASK, e.y);
    }
}

// ---------------------------------------------------------------------------
// init: A16 = fp16(concat(user,item))
// ---------------------------------------------------------------------------
__global__ void init_f16(const float4* __restrict__ user,
                         const float4* __restrict__ item,
                         uint2* __restrict__ A16) {
    int i = blockIdx.x * blockDim.x + threadIdx.x;
    const int n = N_NODES * (DIM / 4);
    if (i >= n) return;
    const int userN = N_USERS * (DIM / 4);
    float4 v = (i < userN) ? user[i] : item[i - userN];
    __half2 h01 = __floats2half2_rn(v.x, v.y);
    __half2 h23 = __floats2half2_rn(v.z, v.w);
    uint2 st;
    st.x = *reinterpret_cast<unsigned*>(&h01);
    st.y = *reinterpret_cast<unsigned*>(&h23);
    A16[i] = st;
}

// ---------------------------------------------------------------------------
// pair-packed pull: one wave per node. half = lane>>5 picks edge 2i / 2i+1 of
// each pair; dpos = lane&31 picks a __half2 (2 dims) of the 64-dim row.
// Each gather instruction fetches TWO edges' rows (2 x 128B). Branchless
// clamped tail (weight := 0) keeps 8 loads in flight every iteration.
// Epilogue: cross-half shuffle-reduce; FINAL fuses the /4 combine.
// ---------------------------------------------------------------------------
template <int FINAL>
__global__ void pull_pair(const __half2* __restrict__ src2,
                          __half2* __restrict__ dst2,
                          const int* __restrict__ row_ptr,
                          const uint2* __restrict__ ent,
                          const float2* __restrict__ user2,
                          const float2* __restrict__ item2,
                          const __half2* __restrict__ L1,
                          const __half2* __restrict__ L2,
                          float2* __restrict__ out2) {
    int node = blockIdx.x * (blockDim.x >> 6) + (threadIdx.x >> 6);
    int lane = threadIdx.x & 63;
    if (node >= N_NODES) return;
    int half = lane >> 5;
    int dpos = lane & 31;

    int beg = row_ptr[node];
    int end = row_ptr[node + 1];

    float accx = 0.0f, accy = 0.0f;
    for (int p0 = beg; p0 < end; p0 += 16) {
        unsigned cols[8];
        float ws[8];
        #pragma unroll
        for (int i = 0; i < 8; ++i) {
            int p = p0 + 2 * i + half;
            uint2 e = ent[min(p, end - 1)];
            cols[i] = e.x;
            ws[i] = (p < end) ? __uint_as_float(e.y) : 0.0f;
        }
        float2 vs[8];
        #pragma unroll
        for (int i = 0; i < 8; ++i)
            vs[i] = __half22float2(src2[(size_t)cols[i] * 32 + dpos]);
        #pragma unroll
        for (int i = 0; i < 8; ++i) {
            accx = fmaf(ws[i], vs[i].x, accx);
            accy = fmaf(ws[i], vs[i].y, accy);
        }
    }

    accx += __shfl_xor(accx, 32);
    accy += __shfl_xor(accy, 32);

    if (half == 0) {
        size_t gi = (size_t)node * 32 + dpos;
        if (FINAL) {
            float2 l0 = (node < N_USERS)
                        ? user2[gi]
                        : item2[(size_t)(node - N_USERS) * 32 + dpos];
            float2 a = __half22float2(L1[gi]);
            float2 b = __half22float2(L2[gi]);
            out2[gi] = make_float2((l0.x + a.x + b.x + accx) * 0.25f,
                                   (l0.y + a.y + b.y + accy) * 0.25f);
        } else {
            dst2[gi] = __floats2half2_rn(accx, accy);
        }
    }
}

extern "C" void kernel_launch(void* const* d_in, const int* in_sizes, int n_in,
                              void* d_out, int out_size, void* d_ws, size_t ws_size,
                              hipStream_t stream) {
    const float* user_w = (const float*)d_in[0];
    const float* item_w = (const float*)d_in[1];
    const int*   eidx   = (const int*)d_in[2];
    const float* ew     = (const float*)d_in[3];

    const int* rows = eidx;             // edge_index[0] (destination)
    const int* cols = eidx + N_EDGES;   // edge_index[1] (source)

    float* out = (float*)d_out;

    // workspace layout (~196 MB)
    __half* A16   = (__half*)d_ws;                           // 38.4 MB (layer0 f16)
    __half* B16   = A16 + (size_t)N_NODES * DIM;             // 38.4 MB (L1)
    __half* C16   = B16 + (size_t)N_NODES * DIM;             // 38.4 MB (L2)
    uint2*  ent1  = (uint2*)(C16 + (size_t)N_NODES * DIM);   // 40 MB (binned)
    uint2*  ent2  = ent1 + N_EDGES;                          // 40 MB (row-sorted)
    int*    boff  = (int*)(ent2 + N_EDGES);                  // NC+1
    int*    bcur  = boff + (NC + 1);                         // NC
    int*    bcnt  = bcur + NC;                               // NC
    int*    bsums = bcnt + NC;                               // SCAN_BLOCKS
    int*    row_ptr = bsums + SCAN_BLOCKS;                   // N_NODES+1

    const int edge_blocks = (N_EDGES + 255) / 256;
    const int node_vec_blocks = (N_NODES * (DIM / 4) + 255) / 256;
    const int pull_blocks = (N_NODES + 3) / 4;               // 4 waves/block

    // ---- build row-sorted CSR via bucket radix ----
    hipMemsetAsync(bcnt, 0, (size_t)NC * sizeof(int), stream);
    hist_bins<<<edge_blocks, 256, 0, stream>>>(rows, bcnt);
    scan_block_g<<<SCAN_BLOCKS, 256, 0, stream>>>(bcnt, boff, bsums, NC);
    scan_sums_g<<<1, 256, 0, stream>>>(bsums, SCAN_BLOCKS);
    finalize_g<<<SCAN_BLOCKS, 256, 0, stream>>>(boff, bsums, bcur, row_ptr);
    bin_fill<<<edge_blocks, 256, 0, stream>>>(rows, cols, ew, bcur, ent1);
    sort_buckets<<<NB, 256, 0, stream>>>(ent1, ent2, boff, row_ptr);

    // ---- layer-0 fp16 snapshot ----
    init_f16<<<node_vec_blocks, 256, 0, stream>>>(
        (const float4*)user_w, (const float4*)item_w, (uint2*)A16);

    // ---- 3 pull layers; #3 fuses the final combine ----
    pull_pair<0><<<pull_blocks, 256, 0, stream>>>(
        (const __half2*)A16, (__half2*)B16, row_ptr, ent2,
        nullptr, nullptr, nullptr, nullptr, nullptr);
    pull_pair<0><<<pull_blocks, 256, 0, stream>>>(
        (const __half2*)B16, (__half2*)C16, row_ptr, ent2,
        nullptr, nullptr, nullptr, nullptr, nullptr);
    pull_pair<1><<<pull_blocks, 256, 0, stream>>>(
        (const __half2*)C16, nullptr, row_ptr, ent2,
        (const float2*)user_w, (const float2*)item_w,
        (const __half2*)B16, (const __half2*)C16, (float2*)out);
}

// Round 7
// 656.409 us; speedup vs baseline: 8.8537x; 1.4845x over previous
//
#include <hip/hip_runtime.h>
#include <hip/hip_fp16.h>

#define N_USERS 200000
#define N_ITEMS 100000
#define N_NODES 300000   // N_USERS + N_ITEMS
#define DIM 64
#define N_EDGES 5000000

#define SB_SHIFT 9
#define SB_ROWS  512                                  // rows per superbucket
#define NSB ((N_NODES + SB_ROWS - 1) / SB_ROWS)       // 586
#define G1 512                                        // workgroups in hist/scatter
#define CHUNK ((N_EDGES + G1 - 1) / G1)               // 9766 edges per wg
#define RSHIFT 20
#define CMASK ((1u << RSHIFT) - 1)                    // col fits 19 bits

// ---------------------------------------------------------------------------
// pass 1: per-workgroup LDS histogram over superbuckets -> dense M[wg][sb].
// No global atomics anywhere in the build.
// ---------------------------------------------------------------------------
__global__ __launch_bounds__(256) void k_hist(const int* __restrict__ rows,
                                              int* __restrict__ M) {
    __shared__ int h[NSB];
    int wg = blockIdx.x, tid = threadIdx.x;
    for (int i = tid; i < NSB; i += 256) h[i] = 0;
    __syncthreads();
    int s0 = wg * CHUNK, s1 = min(s0 + CHUNK, N_EDGES);
    for (int e = s0 + tid; e < s1; e += 256)
        atomicAdd(&h[rows[e] >> SB_SHIFT], 1);        // LDS atomic
    __syncthreads();
    for (int i = tid; i < NSB; i += 256) M[(size_t)wg * NSB + i] = h[i];
}

// ---------------------------------------------------------------------------
// pass 2a: one block per superbucket — exclusive scan of M[0..511][sb] in
// place (Hillis-Steele over 512 with 2 slots/thread); colsums[sb] = total.
// ---------------------------------------------------------------------------
__global__ __launch_bounds__(256) void k_scan_cols(int* __restrict__ M,
                                                   int* __restrict__ colsums) {
    __shared__ int s[G1];
    int sb = blockIdx.x, tid = threadIdx.x;
    int v0 = M[(size_t)tid * NSB + sb];
    int v1 = M[(size_t)(tid + 256) * NSB + sb];
    s[tid] = v0; s[tid + 256] = v1;
    __syncthreads();
    for (int off = 1; off < G1; off <<= 1) {
        int a = (tid >= off) ? s[tid - off] : 0;
        int b = s[tid + 256 - off];
        __syncthreads();
        s[tid] += a; s[tid + 256] += b;
        __syncthreads();
    }
    M[(size_t)tid * NSB + sb] = s[tid] - v0;          // exclusive within column
    M[(size_t)(tid + 256) * NSB + sb] = s[tid + 256] - v1;
    if (tid == 255) colsums[sb] = s[G1 - 1];
}

// ---------------------------------------------------------------------------
// pass 2b: single block — exclusive scan of colsums -> sbbase; sentinels.
// ---------------------------------------------------------------------------
__global__ __launch_bounds__(256) void k_scan_sb(const int* __restrict__ colsums,
                                                 int* __restrict__ sbbase,
                                                 int* __restrict__ row_ptr) {
    __shared__ int s[256];
    __shared__ int carry;
    int tid = threadIdx.x;
    if (tid == 0) carry = 0;
    __syncthreads();
    for (int base = 0; base < NSB; base += 256) {
        int i = base + tid;
        int v = (i < NSB) ? colsums[i] : 0;
        s[tid] = v;
        __syncthreads();
        for (int off = 1; off < 256; off <<= 1) {
            int t = (tid >= off) ? s[tid - off] : 0;
            __syncthreads();
            s[tid] += t;
            __syncthreads();
        }
        if (i < NSB) sbbase[i] = carry + s[tid] - v;
        __syncthreads();
        if (tid == 255) carry += s[255];
        __syncthreads();
    }
    if (tid == 0) { sbbase[NSB] = N_EDGES; row_ptr[N_NODES] = N_EDGES; }
}

// ---------------------------------------------------------------------------
// pass 3: scatter edges to exact precomputed (wg,sb) runs. LDS cursors only;
// each run is ~133B contiguous -> dense line coverage, no cross-XCD ping-pong.
// Entry: x = (localrow << 20) | col, y = weight bits.
// ---------------------------------------------------------------------------
__global__ __launch_bounds__(256) void k_scatter(const int* __restrict__ rows,
                                                 const int* __restrict__ cols,
                                                 const float* __restrict__ w,
                                                 const int* __restrict__ M,
                                                 const int* __restrict__ sbbase,
                                                 uint2* __restrict__ ent1) {
    __shared__ int cur[NSB];
    int wg = blockIdx.x, tid = threadIdx.x;
    for (int i = tid; i < NSB; i += 256)
        cur[i] = sbbase[i] + M[(size_t)wg * NSB + i];
    __syncthreads();
    int s0 = wg * CHUNK, s1 = min(s0 + CHUNK, N_EDGES);
    for (int e = s0 + tid; e < s1; e += 256) {
        int r = rows[e];
        int pos = atomicAdd(&cur[r >> SB_SHIFT], 1);  // LDS atomic
        ent1[pos] = make_uint2(((unsigned)(r & (SB_ROWS - 1)) << RSHIFT) |
                               (unsigned)cols[e],
                               __float_as_uint(w[e]));
    }
}

// ---------------------------------------------------------------------------
// pass 4: one block per superbucket — counting-sort its L2-resident region
// (~68KB) by local row; emit row-sorted ent2 and row_ptr.
// ---------------------------------------------------------------------------
__global__ __launch_bounds__(256) void k_sort_sb(const uint2* __restrict__ ent1,
                                                 uint2* __restrict__ ent2,
                                                 const int* __restrict__ sbbase,
                                                 int* __restrict__ row_ptr) {
    __shared__ int s[SB_ROWS];
    __shared__ int cur[SB_ROWS];
    int sb = blockIdx.x, tid = threadIdx.x;
    int beg = sbbase[sb], end = sbbase[sb + 1];
    s[tid] = 0; s[tid + 256] = 0;
    __syncthreads();
    for (int i = beg + tid; i < end; i += 256)
        atomicAdd(&s[ent1[i].x >> RSHIFT], 1);        // LDS hist
    __syncthreads();
    int o0 = s[tid], o1 = s[tid + 256];
    for (int off = 1; off < SB_ROWS; off <<= 1) {
        int a = (tid >= off) ? s[tid - off] : 0;
        int b = s[tid + 256 - off];
        __syncthreads();
        s[tid] += a; s[tid + 256] += b;
        __syncthreads();
    }
    int b0 = beg + s[tid] - o0;                       // exclusive begins
    int b1 = beg + s[tid + 256] - o1;
    cur[tid] = b0; cur[tid + 256] = b1;
    int gr0 = sb * SB_ROWS + tid, gr1 = gr0 + 256;
    if (gr0 < N_NODES) row_ptr[gr0] = b0;
    if (gr1 < N_NODES) row_ptr[gr1] = b1;
    __syncthreads();
    for (int i = beg + tid; i < end; i += 256) {
        uint2 e = ent1[i];
        int pos = atomicAdd(&cur[e.x >> RSHIFT], 1);  // LDS cursor
        ent2[pos] = make_uint2(e.x & CMASK, e.y);
    }
}

// ---------------------------------------------------------------------------
// init: A16 = fp16(concat(user,item))
// ---------------------------------------------------------------------------
__global__ void init_f16(const float4* __restrict__ user,
                         const float4* __restrict__ item,
                         uint2* __restrict__ A16) {
    int i = blockIdx.x * blockDim.x + threadIdx.x;
    const int n = N_NODES * (DIM / 4);
    if (i >= n) return;
    const int userN = N_USERS * (DIM / 4);
    float4 v = (i < userN) ? user[i] : item[i - userN];
    __half2 h01 = __floats2half2_rn(v.x, v.y);
    __half2 h23 = __floats2half2_rn(v.z, v.w);
    uint2 st;
    st.x = *reinterpret_cast<unsigned*>(&h01);
    st.y = *reinterpret_cast<unsigned*>(&h23);
    A16[i] = st;
}

// ---------------------------------------------------------------------------
// pair-packed pull (unchanged from round 6): one wave per node; half-wave
// picks edge 2i/2i+1; each gather instruction fetches two edges' rows.
// Branchless clamped tail. FINAL fuses the /4 combine.
// ---------------------------------------------------------------------------
template <int FINAL>
__global__ void pull_pair(const __half2* __restrict__ src2,
                          __half2* __restrict__ dst2,
                          const int* __restrict__ row_ptr,
                          const uint2* __restrict__ ent,
                          const float2* __restrict__ user2,
                          const float2* __restrict__ item2,
                          const __half2* __restrict__ L1,
                          const __half2* __restrict__ L2,
                          float2* __restrict__ out2) {
    int node = blockIdx.x * (blockDim.x >> 6) + (threadIdx.x >> 6);
    int lane = threadIdx.x & 63;
    if (node >= N_NODES) return;
    int half = lane >> 5;
    int dpos = lane & 31;

    int beg = row_ptr[node];
    int end = row_ptr[node + 1];

    float accx = 0.0f, accy = 0.0f;
    for (int p0 = beg; p0 < end; p0 += 16) {
        unsigned cols[8];
        float ws[8];
        #pragma unroll
        for (int i = 0; i < 8; ++i) {
            int p = p0 + 2 * i + half;
            uint2 e = ent[min(p, end - 1)];
            cols[i] = e.x;
            ws[i] = (p < end) ? __uint_as_float(e.y) : 0.0f;
        }
        float2 vs[8];
        #pragma unroll
        for (int i = 0; i < 8; ++i)
            vs[i] = __half22float2(src2[(size_t)cols[i] * 32 + dpos]);
        #pragma unroll
        for (int i = 0; i < 8; ++i) {
            accx = fmaf(ws[i], vs[i].x, accx);
            accy = fmaf(ws[i], vs[i].y, accy);
        }
    }

    accx += __shfl_xor(accx, 32);
    accy += __shfl_xor(accy, 32);

    if (half == 0) {
        size_t gi = (size_t)node * 32 + dpos;
        if (FINAL) {
            float2 l0 = (node < N_USERS)
                        ? user2[gi]
                        : item2[(size_t)(node - N_USERS) * 32 + dpos];
            float2 a = __half22float2(L1[gi]);
            float2 b = __half22float2(L2[gi]);
            out2[gi] = make_float2((l0.x + a.x + b.x + accx) * 0.25f,
                                   (l0.y + a.y + b.y + accy) * 0.25f);
        } else {
            dst2[gi] = __floats2half2_rn(accx, accy);
        }
    }
}

extern "C" void kernel_launch(void* const* d_in, const int* in_sizes, int n_in,
                              void* d_out, int out_size, void* d_ws, size_t ws_size,
                              hipStream_t stream) {
    const float* user_w = (const float*)d_in[0];
    const float* item_w = (const float*)d_in[1];
    const int*   eidx   = (const int*)d_in[2];
    const float* ew     = (const float*)d_in[3];

    const int* rows = eidx;             // edge_index[0] (destination)
    const int* cols = eidx + N_EDGES;   // edge_index[1] (source)

    float* out = (float*)d_out;

    // workspace layout (~159 MB)
    __half* A16   = (__half*)d_ws;                           // 38.4 MB
    __half* B16   = A16 + (size_t)N_NODES * DIM;             // 38.4 MB
    uint2*  ent1  = (uint2*)(B16 + (size_t)N_NODES * DIM);   // 40 MB (SB-grouped)
    uint2*  ent2  = ent1 + N_EDGES;                          // 40 MB (row-sorted)
    int*    M       = (int*)(ent2 + N_EDGES);                // G1*NSB (1.2 MB)
    int*    colsums = M + (size_t)G1 * NSB;                  // NSB
    int*    sbbase  = colsums + NSB;                         // NSB+1
    int*    row_ptr = sbbase + (NSB + 1);                    // N_NODES+1

    const int node_vec_blocks = (N_NODES * (DIM / 4) + 255) / 256;
    const int pull_blocks = (N_NODES + 3) / 4;               // 4 waves/block

    // ---- build row-sorted CSR: zero global atomics, dense writes ----
    k_hist<<<G1, 256, 0, stream>>>(rows, M);
    k_scan_cols<<<NSB, 256, 0, stream>>>(M, colsums);
    k_scan_sb<<<1, 256, 0, stream>>>(colsums, sbbase, row_ptr);
    k_scatter<<<G1, 256, 0, stream>>>(rows, cols, ew, M, sbbase, ent1);
    k_sort_sb<<<NSB, 256, 0, stream>>>(ent1, ent2, sbbase, row_ptr);

    // ---- layer-0 fp16 snapshot ----
    init_f16<<<node_vec_blocks, 256, 0, stream>>>(
        (const float4*)user_w, (const float4*)item_w, (uint2*)A16);

    // ---- 3 pull layers (2-buffer ping-pong); #3 fuses the final combine ----
    pull_pair<0><<<pull_blocks, 256, 0, stream>>>(
        (const __half2*)A16, (__half2*)B16, row_ptr, ent2,
        nullptr, nullptr, nullptr, nullptr, nullptr);            // L1 = B16
    pull_pair<0><<<pull_blocks, 256, 0, stream>>>(
        (const __half2*)B16, (__half2*)A16, row_ptr, ent2,
        nullptr, nullptr, nullptr, nullptr, nullptr);            // L2 = A16
    pull_pair<1><<<pull_blocks, 256, 0, stream>>>(
        (const __half2*)A16, nullptr, row_ptr, ent2,
        (const float2*)user_w, (const float2*)item_w,
        (const __half2*)B16, (const __half2*)A16, (float2*)out);
}

// Round 8
// 592.314 us; speedup vs baseline: 9.8117x; 1.1082x over previous
//
#include <hip/hip_runtime.h>
#include <hip/hip_fp16.h>

#define N_USERS 200000
#define N_ITEMS 100000
#define N_NODES 300000   // N_USERS + N_ITEMS
#define DIM 64
#define N_EDGES 5000000

#define SB_SHIFT 9
#define SB_ROWS  512                                  // rows per superbucket
#define NSB ((N_NODES + SB_ROWS - 1) / SB_ROWS)       // 586
#define G1 512                                        // workgroups in hist/scatter
#define CHUNK ((N_EDGES + G1 - 1) / G1)               // 9766 edges per wg
#define RSHIFT 20
#define CMASK ((1u << RSHIFT) - 1)                    // col fits 19 bits

// ---------------------------------------------------------------------------
// pass 1: per-workgroup LDS histogram over superbuckets -> dense M[wg][sb].
// ---------------------------------------------------------------------------
__global__ __launch_bounds__(256) void k_hist(const int* __restrict__ rows,
                                              int* __restrict__ M) {
    __shared__ int h[NSB];
    int wg = blockIdx.x, tid = threadIdx.x;
    for (int i = tid; i < NSB; i += 256) h[i] = 0;
    __syncthreads();
    int s0 = wg * CHUNK, s1 = min(s0 + CHUNK, N_EDGES);
    for (int e = s0 + tid; e < s1; e += 256)
        atomicAdd(&h[rows[e] >> SB_SHIFT], 1);        // LDS atomic
    __syncthreads();
    for (int i = tid; i < NSB; i += 256) M[(size_t)wg * NSB + i] = h[i];
}

// ---------------------------------------------------------------------------
// pass 2a: one block per superbucket — exclusive scan of M[0..511][sb].
// ---------------------------------------------------------------------------
__global__ __launch_bounds__(256) void k_scan_cols(int* __restrict__ M,
                                                   int* __restrict__ colsums) {
    __shared__ int s[G1];
    int sb = blockIdx.x, tid = threadIdx.x;
    int v0 = M[(size_t)tid * NSB + sb];
    int v1 = M[(size_t)(tid + 256) * NSB + sb];
    s[tid] = v0; s[tid + 256] = v1;
    __syncthreads();
    for (int off = 1; off < G1; off <<= 1) {
        int a = (tid >= off) ? s[tid - off] : 0;
        int b = s[tid + 256 - off];
        __syncthreads();
        s[tid] += a; s[tid + 256] += b;
        __syncthreads();
    }
    M[(size_t)tid * NSB + sb] = s[tid] - v0;          // exclusive within column
    M[(size_t)(tid + 256) * NSB + sb] = s[tid + 256] - v1;
    if (tid == 255) colsums[sb] = s[G1 - 1];
}

// ---------------------------------------------------------------------------
// pass 2b: single block — exclusive scan of colsums -> sbbase; sentinels.
// ---------------------------------------------------------------------------
__global__ __launch_bounds__(256) void k_scan_sb(const int* __restrict__ colsums,
                                                 int* __restrict__ sbbase,
                                                 int* __restrict__ row_ptr) {
    __shared__ int s[256];
    __shared__ int carry;
    int tid = threadIdx.x;
    if (tid == 0) carry = 0;
    __syncthreads();
    for (int base = 0; base < NSB; base += 256) {
        int i = base + tid;
        int v = (i < NSB) ? colsums[i] : 0;
        s[tid] = v;
        __syncthreads();
        for (int off = 1; off < 256; off <<= 1) {
            int t = (tid >= off) ? s[tid - off] : 0;
            __syncthreads();
            s[tid] += t;
            __syncthreads();
        }
        if (i < NSB) sbbase[i] = carry + s[tid] - v;
        __syncthreads();
        if (tid == 255) carry += s[255];
        __syncthreads();
    }
    if (tid == 0) { sbbase[NSB] = N_EDGES; row_ptr[N_NODES] = N_EDGES; }
}

// ---------------------------------------------------------------------------
// pass 3: scatter edges to exact precomputed (wg,sb) runs. LDS cursors only.
// Entry: x = (localrow << 20) | col, y = weight bits.
// ---------------------------------------------------------------------------
__global__ __launch_bounds__(256) void k_scatter(const int* __restrict__ rows,
                                                 const int* __restrict__ cols,
                                                 const float* __restrict__ w,
                                                 const int* __restrict__ M,
                                                 const int* __restrict__ sbbase,
                                                 uint2* __restrict__ ent1) {
    __shared__ int cur[NSB];
    int wg = blockIdx.x, tid = threadIdx.x;
    for (int i = tid; i < NSB; i += 256)
        cur[i] = sbbase[i] + M[(size_t)wg * NSB + i];
    __syncthreads();
    int s0 = wg * CHUNK, s1 = min(s0 + CHUNK, N_EDGES);
    for (int e = s0 + tid; e < s1; e += 256) {
        int r = rows[e];
        int pos = atomicAdd(&cur[r >> SB_SHIFT], 1);  // LDS atomic
        ent1[pos] = make_uint2(((unsigned)(r & (SB_ROWS - 1)) << RSHIFT) |
                               (unsigned)cols[e],
                               __float_as_uint(w[e]));
    }
}

// ---------------------------------------------------------------------------
// pass 4: one block per superbucket — counting-sort its L2-resident region
// by local row; emit row-sorted ent2 and row_ptr.
// ---------------------------------------------------------------------------
__global__ __launch_bounds__(256) void k_sort_sb(const uint2* __restrict__ ent1,
                                                 uint2* __restrict__ ent2,
                                                 const int* __restrict__ sbbase,
                                                 int* __restrict__ row_ptr) {
    __shared__ int s[SB_ROWS];
    __shared__ int cur[SB_ROWS];
    int sb = blockIdx.x, tid = threadIdx.x;
    int beg = sbbase[sb], end = sbbase[sb + 1];
    s[tid] = 0; s[tid + 256] = 0;
    __syncthreads();
    for (int i = beg + tid; i < end; i += 256)
        atomicAdd(&s[ent1[i].x >> RSHIFT], 1);        // LDS hist
    __syncthreads();
    int o0 = s[tid], o1 = s[tid + 256];
    for (int off = 1; off < SB_ROWS; off <<= 1) {
        int a = (tid >= off) ? s[tid - off] : 0;
        int b = s[tid + 256 - off];
        __syncthreads();
        s[tid] += a; s[tid + 256] += b;
        __syncthreads();
    }
    int b0 = beg + s[tid] - o0;                       // exclusive begins
    int b1 = beg + s[tid + 256] - o1;
    cur[tid] = b0; cur[tid + 256] = b1;
    int gr0 = sb * SB_ROWS + tid, gr1 = gr0 + 256;
    if (gr0 < N_NODES) row_ptr[gr0] = b0;
    if (gr1 < N_NODES) row_ptr[gr1] = b1;
    __syncthreads();
    for (int i = beg + tid; i < end; i += 256) {
        uint2 e = ent1[i];
        int pos = atomicAdd(&cur[e.x >> RSHIFT], 1);  // LDS cursor
        ent2[pos] = make_uint2(e.x & CMASK, e.y);
    }
}

// ---------------------------------------------------------------------------
// init: A16 = fp16(concat(user,item))
// ---------------------------------------------------------------------------
__global__ void init_f16(const float4* __restrict__ user,
                         const float4* __restrict__ item,
                         uint2* __restrict__ A16) {
    int i = blockIdx.x * blockDim.x + threadIdx.x;
    const int n = N_NODES * (DIM / 4);
    if (i >= n) return;
    const int userN = N_USERS * (DIM / 4);
    float4 v = (i < userN) ? user[i] : item[i - userN];
    __half2 h01 = __floats2half2_rn(v.x, v.y);
    __half2 h23 = __floats2half2_rn(v.z, v.w);
    uint2 st;
    st.x = *reinterpret_cast<unsigned*>(&h01);
    st.y = *reinterpret_cast<unsigned*>(&h23);
    A16[i] = st;
}

__device__ __forceinline__ float2 h2f2u(unsigned u) {
    __half2 h = *reinterpret_cast<__half2*>(&u);
    return __half22float2(h);
}

// ---------------------------------------------------------------------------
// quad-packed pull: one wave per node. Quarter q = lane>>4 owns edges
// p0+4q..p0+4q+3 of each 16-edge chunk; dpos = lane&15 owns dims 4*dpos..+3
// (uint2 = 4 halves = 8B/lane -> 16 lanes cover a 128B row). One gather
// instruction fetches FOUR edges' rows. Branchless clamped tail (w := 0).
// Epilogue: 2-stage cross-quarter shuffle reduce; FINAL fuses /4 combine.
// ---------------------------------------------------------------------------
template <int FINAL>
__global__ void pull_quad(const uint2* __restrict__ src4,   // node row = 16 uint2
                          uint2* __restrict__ dst4,
                          const int* __restrict__ row_ptr,
                          const uint2* __restrict__ ent,
                          const float4* __restrict__ user4,  // node row = 16 float4
                          const float4* __restrict__ item4,
                          const uint2* __restrict__ L1,
                          const uint2* __restrict__ L2,
                          float4* __restrict__ out4) {
    int node = blockIdx.x * (blockDim.x >> 6) + (threadIdx.x >> 6);
    int lane = threadIdx.x & 63;
    if (node >= N_NODES) return;
    int q = lane >> 4;                 // quarter 0..3
    int dpos = lane & 15;              // dim group (4 dims)

    int beg = row_ptr[node];
    int end = row_ptr[node + 1];

    float a0 = 0.0f, a1 = 0.0f, a2 = 0.0f, a3 = 0.0f;
    for (int p0 = beg; p0 < end; p0 += 16) {
        unsigned cols[4];
        float ws[4];
        #pragma unroll
        for (int i = 0; i < 4; ++i) {
            int p = p0 + 4 * q + i;
            uint2 e = ent[min(p, end - 1)];
            cols[i] = e.x;
            ws[i] = (p < end) ? __uint_as_float(e.y) : 0.0f;
        }
        uint2 vs[4];
        #pragma unroll
        for (int i = 0; i < 4; ++i)
            vs[i] = src4[(size_t)cols[i] * 16 + dpos];
        #pragma unroll
        for (int i = 0; i < 4; ++i) {
            float2 f01 = h2f2u(vs[i].x);
            float2 f23 = h2f2u(vs[i].y);
            a0 = fmaf(ws[i], f01.x, a0);
            a1 = fmaf(ws[i], f01.y, a1);
            a2 = fmaf(ws[i], f23.x, a2);
            a3 = fmaf(ws[i], f23.y, a3);
        }
    }

    // reduce across quarters (lane bits 4 and 5)
    a0 += __shfl_xor(a0, 16); a0 += __shfl_xor(a0, 32);
    a1 += __shfl_xor(a1, 16); a1 += __shfl_xor(a1, 32);
    a2 += __shfl_xor(a2, 16); a2 += __shfl_xor(a2, 32);
    a3 += __shfl_xor(a3, 16); a3 += __shfl_xor(a3, 32);

    if (q == 0) {
        size_t gi = (size_t)node * 16 + dpos;
        if (FINAL) {
            float4 l0 = (node < N_USERS)
                        ? user4[gi]
                        : item4[(size_t)(node - N_USERS) * 16 + dpos];
            uint2 u1 = L1[gi], u2 = L2[gi];
            float2 b01 = h2f2u(u1.x), b23 = h2f2u(u1.y);
            float2 c01 = h2f2u(u2.x), c23 = h2f2u(u2.y);
            float4 r;
            r.x = (l0.x + b01.x + c01.x + a0) * 0.25f;
            r.y = (l0.y + b01.y + c01.y + a1) * 0.25f;
            r.z = (l0.z + b23.x + c23.x + a2) * 0.25f;
            r.w = (l0.w + b23.y + c23.y + a3) * 0.25f;
            out4[gi] = r;
        } else {
            __half2 h01 = __floats2half2_rn(a0, a1);
            __half2 h23 = __floats2half2_rn(a2, a3);
            uint2 st;
            st.x = *reinterpret_cast<unsigned*>(&h01);
            st.y = *reinterpret_cast<unsigned*>(&h23);
            dst4[gi] = st;
        }
    }
}

extern "C" void kernel_launch(void* const* d_in, const int* in_sizes, int n_in,
                              void* d_out, int out_size, void* d_ws, size_t ws_size,
                              hipStream_t stream) {
    const float* user_w = (const float*)d_in[0];
    const float* item_w = (const float*)d_in[1];
    const int*   eidx   = (const int*)d_in[2];
    const float* ew     = (const float*)d_in[3];

    const int* rows = eidx;             // edge_index[0] (destination)
    const int* cols = eidx + N_EDGES;   // edge_index[1] (source)

    float* out = (float*)d_out;

    // workspace layout (~159 MB)
    __half* A16   = (__half*)d_ws;                           // 38.4 MB
    __half* B16   = A16 + (size_t)N_NODES * DIM;             // 38.4 MB
    uint2*  ent1  = (uint2*)(B16 + (size_t)N_NODES * DIM);   // 40 MB (SB-grouped)
    uint2*  ent2  = ent1 + N_EDGES;                          // 40 MB (row-sorted)
    int*    M       = (int*)(ent2 + N_EDGES);                // G1*NSB (1.2 MB)
    int*    colsums = M + (size_t)G1 * NSB;                  // NSB
    int*    sbbase  = colsums + NSB;                         // NSB+1
    int*    row_ptr = sbbase + (NSB + 1);                    // N_NODES+1

    const int node_vec_blocks = (N_NODES * (DIM / 4) + 255) / 256;
    const int pull_blocks = (N_NODES + 3) / 4;               // 4 waves/block

    // ---- build row-sorted CSR: zero global atomics, dense writes ----
    k_hist<<<G1, 256, 0, stream>>>(rows, M);
    k_scan_cols<<<NSB, 256, 0, stream>>>(M, colsums);
    k_scan_sb<<<1, 256, 0, stream>>>(colsums, sbbase, row_ptr);
    k_scatter<<<G1, 256, 0, stream>>>(rows, cols, ew, M, sbbase, ent1);
    k_sort_sb<<<NSB, 256, 0, stream>>>(ent1, ent2, sbbase, row_ptr);

    // ---- layer-0 fp16 snapshot ----
    init_f16<<<node_vec_blocks, 256, 0, stream>>>(
        (const float4*)user_w, (const float4*)item_w, (uint2*)A16);

    // ---- 3 pull layers (2-buffer ping-pong); #3 fuses the final combine ----
    pull_quad<0><<<pull_blocks, 256, 0, stream>>>(
        (const uint2*)A16, (uint2*)B16, row_ptr, ent2,
        nullptr, nullptr, nullptr, nullptr, nullptr);            // L1 = B16
    pull_quad<0><<<pull_blocks, 256, 0, stream>>>(
        (const uint2*)B16, (uint2*)A16, row_ptr, ent2,
        nullptr, nullptr, nullptr, nullptr, nullptr);            // L2 = A16
    pull_quad<1><<<pull_blocks, 256, 0, stream>>>(
        (const uint2*)A16, nullptr, row_ptr, ent2,
        (const float4*)user_w, (const float4*)item_w,
        (const uint2*)B16, (const uint2*)A16, (float4*)out);
}